// Round 7
// baseline (1022.541 us; speedup 1.0000x reference)
//
#include <hip/hip_runtime.h>

#define N_NODES 45000
#define F_NNZ   33
#define NUM_STEPS 30
#define HCHUNK  100
#define NHEADBLK (N_NODES / HCHUNK)   // 450

__device__ inline float bf2f(unsigned short u) {
    return __uint_as_float(((unsigned int)u) << 16);
}
__device__ inline unsigned short f2bf(float f) {
    unsigned int x = __float_as_uint(f);
    unsigned int r = (x + 0x7fffu + ((x >> 16) & 1u)) >> 16;   // RNE
    return (unsigned short)r;
}

// pk[t] = (bf16(values[t]) << 16) | u16(idx[t])   — 4 B per nnz entry
__global__ __launch_bounds__(256) void pack_kernel(const int* __restrict__ idx,
                                                   const float* __restrict__ values,
                                                   unsigned int* __restrict__ pk) {
    int t = blockIdx.x * 256 + threadIdx.x;
    if (t >= N_NODES * F_NNZ) return;
    unsigned int vb = f2bf(values[t]);
    pk[t] = (vb << 16) | (unsigned int)idx[t];
}

// x (B=64, N) -> split transposed halves: xT{0,1} fp32 (N,32), g0{0,1} = bf16(2x)
__global__ __launch_bounds__(256) void transpose_init(const float* __restrict__ x,
                                                      float* __restrict__ xT0,
                                                      float* __restrict__ xT1,
                                                      unsigned short* __restrict__ g0,
                                                      unsigned short* __restrict__ g1) {
    __shared__ float tile[64][65];
    int n0  = blockIdx.x * 64;
    int t   = threadIdx.x;
    int ln  = t & 63;
    int sub = t >> 6;
    for (int bb = 0; bb < 16; ++bb) {
        int b = bb * 4 + sub;
        int n = n0 + ln;
        float v = (n < N_NODES) ? x[(size_t)b * N_NODES + n] : 0.f;
        tile[ln][b] = v;
    }
    __syncthreads();
    for (int nn = 0; nn < 16; ++nn) {
        int nrel = nn * 4 + sub;
        int n = n0 + nrel;
        if (n < N_NODES) {
            float v = tile[nrel][ln];         // ln = b
            int half = ln >> 5, l32 = ln & 31;
            size_t pos = (size_t)n * 32 + l32;
            (half ? xT1 : xT0)[pos] = v;
            (half ? g1 : g0)[pos] = f2bf(2.f * v);
        }
    }
}

// One launch per step, both halves, XCD-pinned (blockIdx&7 -> XCD; XCDs 0-3 =
// half 0, XCDs 4-7 = half 1). Gather source gIn (2.88 MB/half) is the ONLY
// stream allowed to allocate in L2: pk+bias staged through LDS with nt loads,
// xT nt-loaded, gOut nt-stored. Block = 8 consecutive rows (4 waves x 2 rows).
__global__ __launch_bounds__(256) void step_kernel(const unsigned short* __restrict__ g0In,
                                                   const unsigned short* __restrict__ g1In,
                                                   const float* __restrict__ xT0,
                                                   const float* __restrict__ xT1,
                                                   const unsigned int* __restrict__ pk,
                                                   const float* __restrict__ bias,
                                                   unsigned short* __restrict__ g0Out,
                                                   unsigned short* __restrict__ g1Out,
                                                   int addX) {
    int b    = (int)blockIdx.x;
    int xcd  = b & 7;
    int half = xcd >> 2;
    int sub  = ((b >> 3) << 2) | (xcd & 3);   // block index within half
    if (sub >= 5625) return;

    __shared__ unsigned int spk[264];
    __shared__ float sbias[8];
    int t = threadIdx.x;
    for (int i = t; i < 264; i += 256)
        spk[i] = __builtin_nontemporal_load(&pk[(size_t)sub * 264 + i]);
    if (t < 8)
        sbias[t] = __builtin_nontemporal_load(&bias[sub * 8 + t]);
    __syncthreads();

    int wid  = t >> 6;
    int lane = t & 63;
    int rowsel = lane >> 5;
    int l32    = lane & 31;

    const unsigned short* gIn  = half ? g1In  : g0In;
    const float*          xT   = half ? xT1   : xT0;
    unsigned short*       gOut = half ? g1Out : g0Out;

    const unsigned int* sp = &spk[wid * 66 + rowsel * 33];
    float acc = 0.f;
#pragma unroll
    for (int f = 0; f < F_NNZ; ++f) {
        unsigned int e = sp[f];                        // LDS broadcast (2 addrs/wave)
        int   j = (int)(e & 0xffffu);
        float v = __uint_as_float(e & 0xffff0000u);    // bf16 value in high bits
        acc = fmaf(v, bf2f(gIn[(size_t)j * 32 + l32]), acc);
    }
    int n = sub * 8 + wid * 2 + rowsel;
    float tv = fmaxf(acc + sbias[wid * 2 + rowsel], 0.f);
    size_t o = (size_t)n * 32 + l32;
    float ov = tv;
    if (addX) ov += __builtin_nontemporal_load(&xT[o]);
    __builtin_nontemporal_store(f2bf(ov), &gOut[o]);
}

// Head GEMM partials, no atomics. lane = b (coalesced h-row load), wave w owns
// h in [16w, 16w+16). Partial layout is [h][b] (h*64 + b).
__global__ __launch_bounds__(256) void head_partial4(const unsigned short* __restrict__ h0,
                                                     const unsigned short* __restrict__ h1,
                                                     const float* __restrict__ w1,
                                                     float* __restrict__ partial) {
    int lane = threadIdx.x & 63;   // b
    int w    = threadIdx.x >> 6;   // h-group
    const unsigned short* hh = (lane >> 5) ? h1 : h0;
    int l32  = lane & 31;
    int n0   = blockIdx.x * HCHUNK;
    float acc[16];
#pragma unroll
    for (int k = 0; k < 16; ++k) acc[k] = 0.f;
    for (int i = 0; i < HCHUNK; ++i) {
        int n = n0 + i;
        float hv = bf2f(hh[(size_t)n * 32 + l32]);           // coalesced
        const float* wrow = w1 + (size_t)n * 64 + w * 16;    // wave-uniform
#pragma unroll
        for (int k = 0; k < 16; ++k)
            acc[k] = fmaf(hv, wrow[k], acc[k]);
    }
    float* pp = partial + (size_t)blockIdx.x * 4096;
#pragma unroll
    for (int k = 0; k < 16; ++k)
        pp[(size_t)(w * 16 + k) * 64 + lane] = acc[k];       // [h][b]
}

// hidAcc[t] = sum over chunks of partial[chunk][t]  (layout [h][b] preserved)
__global__ __launch_bounds__(256) void head_reduce(const float* __restrict__ partial,
                                                   float* __restrict__ hidAcc) {
    int t = blockIdx.x * 256 + threadIdx.x;
    float acc = 0.f;
    for (int i = 0; i < NHEADBLK; ++i) acc += partial[(size_t)i * 4096 + t];
    hidAcc[t] = acc;
}

// out[b][c] = b2[c] + sum_h relu(hid[h][b] + b1[h]) * w2[h][c]   (hidAcc is [h][b])
__global__ __launch_bounds__(1024) void head_final(const float* __restrict__ hidAcc,
                                                   const float* __restrict__ b1,
                                                   const float* __restrict__ w2,
                                                   const float* __restrict__ b2,
                                                   float* __restrict__ out) {
    int t = threadIdx.x;
    if (t >= 640) return;
    int b = t / 10, c = t % 10;
    float acc = b2[c];
#pragma unroll
    for (int h = 0; h < 64; ++h) {
        float hv = fmaxf(hidAcc[h * 64 + b] + b1[h], 0.f);   // transposed read
        acc = fmaf(hv, w2[h * 10 + c], acc);
    }
    out[t] = acc;
}

extern "C" void kernel_launch(void* const* d_in, const int* in_sizes, int n_in,
                              void* d_out, int out_size, void* d_ws, size_t ws_size,
                              hipStream_t stream) {
    const float* x      = (const float*)d_in[0];
    const float* values = (const float*)d_in[1];
    const float* bias   = (const float*)d_in[2];
    const float* w1     = (const float*)d_in[3];
    const float* b1     = (const float*)d_in[4];
    const float* w2     = (const float*)d_in[5];
    const float* b2     = (const float*)d_in[6];
    const int*   idx    = (const int*)d_in[7];
    float* out = (float*)d_out;

    size_t perHalfF = (size_t)N_NODES * 32;
    float*          xT0 = (float*)d_ws;                        // 5.76 MB
    float*          xT1 = xT0 + perHalfF;                      // 5.76 MB
    unsigned short* gA0 = (unsigned short*)(xT1 + perHalfF);   // 2.88 MB each
    unsigned short* gB0 = gA0 + perHalfF;
    unsigned short* gA1 = gB0 + perHalfF;
    unsigned short* gB1 = gA1 + perHalfF;
    unsigned int*   pk  = (unsigned int*)(gB1 + perHalfF);     // 5.94 MB
    float*          partial = (float*)(pk + (size_t)N_NODES * F_NNZ);  // 7.37 MB
    float*          hidAcc  = partial + (size_t)NHEADBLK * 4096;       // 16 KB

    pack_kernel<<<(N_NODES * F_NNZ + 255) / 256, 256, 0, stream>>>(idx, values, pk);
    transpose_init<<<(N_NODES + 63) / 64, 256, 0, stream>>>(x, xT0, xT1, gA0, gA1);

    const unsigned short* gin0 = gA0; unsigned short* gout0 = gB0;
    const unsigned short* gin1 = gA1; unsigned short* gout1 = gB1;
    for (int s = 0; s < NUM_STEPS; ++s) {
        int addX = (s < NUM_STEPS - 1) ? 1 : 0;
        step_kernel<<<11264, 256, 0, stream>>>(gin0, gin1, xT0, xT1, pk, bias,
                                               gout0, gout1, addX);
        unsigned short* t0 = (unsigned short*)gin0; gin0 = gout0; gout0 = t0;
        unsigned short* t1 = (unsigned short*)gin1; gin1 = gout1; gout1 = t1;
    }

    head_partial4<<<NHEADBLK, 256, 0, stream>>>(gin0, gin1, w1, partial);
    head_reduce<<<16, 256, 0, stream>>>(partial, hidAcc);
    head_final<<<1, 1024, 0, stream>>>(hidAcc, b1, w2, b2, out);
}

// Round 8
// 896.221 us; speedup vs baseline: 1.1409x; 1.1409x over previous
//
#include <hip/hip_runtime.h>

#define N_NODES 45000
#define F_NNZ   33
#define NUM_STEPS 30
#define HCHUNK  100
#define NHEADBLK (N_NODES / HCHUNK)   // 450

__device__ inline float bf2f(unsigned short u) {
    return __uint_as_float(((unsigned int)u) << 16);
}
__device__ inline unsigned short f2bf(float f) {
    unsigned int x = __float_as_uint(f);
    unsigned int r = (x + 0x7fffu + ((x >> 16) & 1u)) >> 16;   // RNE
    return (unsigned short)r;
}

// pk[t] = (bf16(values[t]) << 16) | u16(idx[t])   — 4 B per nnz entry
__global__ __launch_bounds__(256) void pack_kernel(const int* __restrict__ idx,
                                                   const float* __restrict__ values,
                                                   unsigned int* __restrict__ pk) {
    int t = blockIdx.x * 256 + threadIdx.x;
    if (t >= N_NODES * F_NNZ) return;
    unsigned int vb = f2bf(values[t]);
    pk[t] = (vb << 16) | (unsigned int)idx[t];
}

// x (B=64, N) -> split transposed halves: xT{0,1} fp32 (N,32), g0{0,1} = bf16(2x)
__global__ __launch_bounds__(256) void transpose_init(const float* __restrict__ x,
                                                      float* __restrict__ xT0,
                                                      float* __restrict__ xT1,
                                                      unsigned short* __restrict__ g0,
                                                      unsigned short* __restrict__ g1) {
    __shared__ float tile[64][65];
    int n0  = blockIdx.x * 64;
    int t   = threadIdx.x;
    int ln  = t & 63;
    int sub = t >> 6;
    for (int bb = 0; bb < 16; ++bb) {
        int b = bb * 4 + sub;
        int n = n0 + ln;
        float v = (n < N_NODES) ? x[(size_t)b * N_NODES + n] : 0.f;
        tile[ln][b] = v;
    }
    __syncthreads();
    for (int nn = 0; nn < 16; ++nn) {
        int nrel = nn * 4 + sub;
        int n = n0 + nrel;
        if (n < N_NODES) {
            float v = tile[nrel][ln];         // ln = b
            int half = ln >> 5, l32 = ln & 31;
            size_t pos = (size_t)n * 32 + l32;
            (half ? xT1 : xT0)[pos] = v;
            (half ? g1 : g0)[pos] = f2bf(2.f * v);
        }
    }
}

// Persistent-style step: 2048 blocks = 8 blocks/CU, 32 waves/CU resident.
// XCD-pinned (blockIdx&7 -> XCD; XCDs 0-3 = half 0, XCDs 4-7 = half 1).
// Each wave grid-strides over row-pairs (lanes 0-31 row n0, 32-63 row n0+1),
// keeping ~33 gathers in flight per wave at steady state.
__global__ __launch_bounds__(256, 8) void step_kernel(const unsigned short* __restrict__ g0In,
                                                      const unsigned short* __restrict__ g1In,
                                                      const float* __restrict__ xT0,
                                                      const float* __restrict__ xT1,
                                                      const unsigned int* __restrict__ pk,
                                                      const float* __restrict__ bias,
                                                      unsigned short* __restrict__ g0Out,
                                                      unsigned short* __restrict__ g1Out,
                                                      int addX) {
    int b    = (int)blockIdx.x;
    int xcd  = b & 7;
    int half = xcd >> 2;
    int sub  = ((b >> 3) << 2) | (xcd & 3);   // 0..1023 within half
    int wid  = threadIdx.x >> 6;
    int lane = threadIdx.x & 63;
    int rowsel = lane >> 5;
    int l32    = lane & 31;

    const unsigned short* gIn  = half ? g1In  : g0In;
    const float*          xT   = half ? xT1   : xT0;
    unsigned short*       gOut = half ? g1Out : g0Out;

    int w = sub * 4 + wid;                    // 0..4095 wave id within half
    for (int rp = w; rp < N_NODES / 2; rp += 4096) {
        int n0 = __builtin_amdgcn_readfirstlane(rp * 2);
        const unsigned int* p = pk + (size_t)n0 * F_NNZ;   // rows n0,n0+1: 66 dwords
        float acc = 0.f;
#pragma unroll
        for (int f = 0; f < F_NNZ; ++f) {
            unsigned int e0 = p[f];            // wave-uniform -> scalar load
            unsigned int e1 = p[f + F_NNZ];
            unsigned int e  = rowsel ? e1 : e0;
            int   j = (int)(e & 0xffffu);
            float v = __uint_as_float(e & 0xffff0000u);    // bf16 value in high bits
            acc = fmaf(v, bf2f(gIn[(size_t)j * 32 + l32]), acc);
        }
        int n = n0 + rowsel;
        float tv = fmaxf(acc + bias[n], 0.f);
        size_t o = (size_t)n * 32 + l32;
        float ov = tv;
        if (addX) ov += __builtin_nontemporal_load(&xT[o]);
        __builtin_nontemporal_store(f2bf(ov), &gOut[o]);
    }
}

// Head GEMM partials, no atomics. lane = b (coalesced h-row load), wave w owns
// h in [16w, 16w+16). Partial layout is [h][b] (h*64 + b).
__global__ __launch_bounds__(256) void head_partial4(const unsigned short* __restrict__ h0,
                                                     const unsigned short* __restrict__ h1,
                                                     const float* __restrict__ w1,
                                                     float* __restrict__ partial) {
    int lane = threadIdx.x & 63;   // b
    int w    = threadIdx.x >> 6;   // h-group
    const unsigned short* hh = (lane >> 5) ? h1 : h0;
    int l32  = lane & 31;
    int n0   = blockIdx.x * HCHUNK;
    float acc[16];
#pragma unroll
    for (int k = 0; k < 16; ++k) acc[k] = 0.f;
    for (int i = 0; i < HCHUNK; ++i) {
        int n = n0 + i;
        float hv = bf2f(hh[(size_t)n * 32 + l32]);           // coalesced
        const float* wrow = w1 + (size_t)n * 64 + w * 16;    // wave-uniform
#pragma unroll
        for (int k = 0; k < 16; ++k)
            acc[k] = fmaf(hv, wrow[k], acc[k]);
    }
    float* pp = partial + (size_t)blockIdx.x * 4096;
#pragma unroll
    for (int k = 0; k < 16; ++k)
        pp[(size_t)(w * 16 + k) * 64 + lane] = acc[k];       // [h][b]
}

// hidAcc[t] = sum over chunks of partial[chunk][t]  (layout [h][b] preserved)
__global__ __launch_bounds__(256) void head_reduce(const float* __restrict__ partial,
                                                   float* __restrict__ hidAcc) {
    int t = blockIdx.x * 256 + threadIdx.x;
    float acc = 0.f;
    for (int i = 0; i < NHEADBLK; ++i) acc += partial[(size_t)i * 4096 + t];
    hidAcc[t] = acc;
}

// out[b][c] = b2[c] + sum_h relu(hid[h][b] + b1[h]) * w2[h][c]   (hidAcc is [h][b])
__global__ __launch_bounds__(1024) void head_final(const float* __restrict__ hidAcc,
                                                   const float* __restrict__ b1,
                                                   const float* __restrict__ w2,
                                                   const float* __restrict__ b2,
                                                   float* __restrict__ out) {
    int t = threadIdx.x;
    if (t >= 640) return;
    int b = t / 10, c = t % 10;
    float acc = b2[c];
#pragma unroll
    for (int h = 0; h < 64; ++h) {
        float hv = fmaxf(hidAcc[h * 64 + b] + b1[h], 0.f);   // transposed read
        acc = fmaf(hv, w2[h * 10 + c], acc);
    }
    out[t] = acc;
}

extern "C" void kernel_launch(void* const* d_in, const int* in_sizes, int n_in,
                              void* d_out, int out_size, void* d_ws, size_t ws_size,
                              hipStream_t stream) {
    const float* x      = (const float*)d_in[0];
    const float* values = (const float*)d_in[1];
    const float* bias   = (const float*)d_in[2];
    const float* w1     = (const float*)d_in[3];
    const float* b1     = (const float*)d_in[4];
    const float* w2     = (const float*)d_in[5];
    const float* b2     = (const float*)d_in[6];
    const int*   idx    = (const int*)d_in[7];
    float* out = (float*)d_out;

    size_t perHalfF = (size_t)N_NODES * 32;
    float*          xT0 = (float*)d_ws;                        // 5.76 MB
    float*          xT1 = xT0 + perHalfF;                      // 5.76 MB
    unsigned short* gA0 = (unsigned short*)(xT1 + perHalfF);   // 2.88 MB each
    unsigned short* gB0 = gA0 + perHalfF;
    unsigned short* gA1 = gB0 + perHalfF;
    unsigned short* gB1 = gA1 + perHalfF;
    unsigned int*   pk  = (unsigned int*)(gB1 + perHalfF);     // 5.94 MB
    float*          partial = (float*)(pk + (size_t)N_NODES * F_NNZ);  // 7.37 MB
    float*          hidAcc  = partial + (size_t)NHEADBLK * 4096;       // 16 KB

    pack_kernel<<<(N_NODES * F_NNZ + 255) / 256, 256, 0, stream>>>(idx, values, pk);
    transpose_init<<<(N_NODES + 63) / 64, 256, 0, stream>>>(x, xT0, xT1, gA0, gA1);

    const unsigned short* gin0 = gA0; unsigned short* gout0 = gB0;
    const unsigned short* gin1 = gA1; unsigned short* gout1 = gB1;
    for (int s = 0; s < NUM_STEPS; ++s) {
        int addX = (s < NUM_STEPS - 1) ? 1 : 0;
        step_kernel<<<2048, 256, 0, stream>>>(gin0, gin1, xT0, xT1, pk, bias,
                                              gout0, gout1, addX);
        unsigned short* t0 = (unsigned short*)gin0; gin0 = gout0; gout0 = t0;
        unsigned short* t1 = (unsigned short*)gin1; gin1 = gout1; gout1 = t1;
    }

    head_partial4<<<NHEADBLK, 256, 0, stream>>>(gin0, gin1, w1, partial);
    head_reduce<<<16, 256, 0, stream>>>(partial, hidAcc);
    head_final<<<1, 1024, 0, stream>>>(hidAcc, b1, w2, b2, out);
}